// Round 7
// baseline (282.698 us; speedup 1.0000x reference)
//
#include <hip/hip_runtime.h>
#include <hip/hip_bf16.h>

#define NUM_CLASSES 100000
#define DIM 256
#define BATCH 256
#define NUM_TRUE 1024
#define NUM_SAMPLED 16384
// ln(NUM_CLASSES + 1)
#define LOG_RANGE 11.51293546492023f
#define INV_LOG_RANGE (1.0f / LOG_RANGE)

#define SBLOCKS 512      // sampled blocks (32 s-rows each), scheduled FIRST
#define NBUCKET 3125     // class buckets of 32 sequential classes (100000 = 3125*32)
#define NB2     3328     // 13*256, padded bucket stride for coalesced reduce
#define CAP     512      // pair slots per bucket (avg 84, huge margin)
#define COMB_THREADS 100096  // 391 blocks * 256

typedef __bf16 bf16x8 __attribute__((ext_vector_type(8)));
typedef float  f32x4  __attribute__((ext_vector_type(4)));

// RNE float -> bf16 bits
static __device__ __forceinline__ unsigned short f2bf(float f) {
    unsigned int u = __float_as_uint(f);
    unsigned int lsb = (u >> 16) & 1u;
    u += 0x7fffu + lsb;
    return (unsigned short)(u >> 16);
}

// -log(expected_count(id)), precise libm (once per class, comb_kernel only)
static __device__ __forceinline__ float neg_log_ec(int id) {
    float idf = (float)id;
    float p = logf((idf + 2.0f) / (idf + 1.0f)) * INV_LOG_RANGE;
    float ec = -expm1f((float)NUM_SAMPLED * log1pf(-p));
    return -logf(ec);
}

// ---- comb[c] = bias[c] - log(ec(c)); inputs fp32 -> bf16;
//      bin all (b,label) pairs into class-range buckets (cursor pre-zeroed) ----
__global__ __launch_bounds__(256) void comb_kernel(const float* __restrict__ bias,
                                                   const float* __restrict__ inputs,
                                                   const int* __restrict__ labels,
                                                   float* __restrict__ comb,
                                                   unsigned short* __restrict__ inbf,
                                                   int* __restrict__ cursor,
                                                   unsigned int* __restrict__ pairs) {
    int c = blockIdx.x * 256 + threadIdx.x;
    if (c < NUM_CLASSES) comb[c] = bias[c] + neg_log_ec(c);
    if (c < BATCH * DIM) inbf[c] = f2bf(inputs[c]);
    for (int g = c; g < BATCH * NUM_TRUE; g += COMB_THREADS) {
        int lbl = labels[g];
        int bk = lbl >> 5;
        int pos = atomicAdd(&cursor[bk], 1);
        if (pos < CAP)
            pairs[(size_t)bk * CAP + pos] = ((unsigned int)(g >> 10) << 17) | (unsigned int)lbl;
    }
}

// staging tile (bf16) and logit tile (fp32) alias: lw is dead after af-preload
union SMem {
    unsigned short lw[32][264];   // 16.9 KB, live: stage -> af preload
    float          lgt[32][257];  // 32.9 KB, live: t-loop -> pair epilogue
};

// ---------------- fused kernel: sampled blocks, then bucket blocks -------------
// True path = dense MFMA over 32-class windows: w streamed sequentially (one
// coalesced 100 MB pass at full HBM BW instead of 268 MB of random gathers at
// 2.2 TB/s), all 32x256 logits computed by the proven MFMA tile, pair epilogue
// reads them from LDS.
__global__ __launch_bounds__(256) void fused_kernel(const float* __restrict__ inputs,
                                                    const float* __restrict__ w,
                                                    const float* __restrict__ comb,
                                                    const int* __restrict__ sampled,
                                                    const unsigned short* __restrict__ inbf,
                                                    const int* __restrict__ cursor,
                                                    const unsigned int* __restrict__ pairs,
                                                    float* __restrict__ ptrue,
                                                    float* __restrict__ partial) {
    __shared__ SMem u;
    __shared__ float cs[32];
    __shared__ float bacc[BATCH];

    const int tid   = threadIdx.x;
    const int inner = tid & 15;
    const int r16   = tid >> 4;
    const int lane  = tid & 63;
    const int wv    = tid >> 6;
    const int m     = lane & 15;
    const int quad  = lane >> 4;
    const int shalf = (wv >> 1) * 16;    // which 16 rows
    const int bhalf = (wv & 1) * 128;    // which 128 batch cols

    bacc[tid] = 0.0f;

    if (blockIdx.x < SBLOCKS) {
        // ================= sampled path (unchanged structure) ==================
        const int sblk = blockIdx.x;
        const int s0 = sblk * 32;

        #pragma unroll
        for (int rb = 0; rb < 2; ++rb) {
            const int r = rb * 16 + r16;
            const int id = sampled[s0 + r];
            const float* src = w + (size_t)id * DIM;
            #pragma unroll
            for (int j = 0; j < 4; ++j) {
                float4 v = *(const float4*)(src + j * 64 + inner * 4);
                ushort4 pk;
                pk.x = f2bf(v.x); pk.y = f2bf(v.y); pk.z = f2bf(v.z); pk.w = f2bf(v.w);
                *(ushort4*)(&u.lw[r][j * 64 + inner * 4]) = pk;
            }
        }
        if (tid < 32) cs[tid] = comb[sampled[s0 + tid]];
        __syncthreads();

        bf16x8 af[8];
        #pragma unroll
        for (int kk = 0; kk < 8; ++kk)
            af[kk] = *(const bf16x8*)(&u.lw[shalf + m][kk * 32 + quad * 8]);

        #pragma unroll
        for (int t = 0; t < 8; ++t) {
            const int brow = bhalf + t * 16 + m;
            const unsigned short* bp = inbf + brow * DIM;
            bf16x8 bf[8];
            #pragma unroll
            for (int kk = 0; kk < 8; ++kk)
                bf[kk] = *(const bf16x8*)(bp + kk * 32 + quad * 8);
            f32x4 acc = {0, 0, 0, 0};
            #pragma unroll
            for (int kk = 0; kk < 8; ++kk)
                acc = __builtin_amdgcn_mfma_f32_16x16x32_bf16(af[kk], bf[kk], acc, 0, 0, 0);
            float ps = 0.0f;
            #pragma unroll
            for (int r = 0; r < 4; ++r) {
                float c = cs[shalf + quad * 4 + r];
                float l = acc[r] + c;
                ps += fmaxf(l, 0.0f) + __logf(1.0f + __expf(-fabsf(l)));
            }
            ps += __shfl_xor(ps, 16); ps += __shfl_xor(ps, 32);
            if (quad == 0) atomicAdd(&bacc[bhalf + t * 16 + m], ps);
        }
        __syncthreads();
        partial[tid * SBLOCKS + sblk] = bacc[tid];   // [b][sblk], non-atomic
    } else {
        // ============ true path: dense MFMA over a 32-class window =============
        const int tb = blockIdx.x - SBLOCKS;
        const int s0 = tb * 32;

        // stage 32 SEQUENTIAL w rows -> bf16 LDS (fully coalesced 32 KB stream)
        const float* wb = w + (size_t)s0 * DIM;
        #pragma unroll
        for (int rb = 0; rb < 2; ++rb) {
            const int r = rb * 16 + r16;
            const float* src = wb + r * DIM;
            #pragma unroll
            for (int j = 0; j < 4; ++j) {
                float4 v = *(const float4*)(src + j * 64 + inner * 4);
                ushort4 pk;
                pk.x = f2bf(v.x); pk.y = f2bf(v.y); pk.z = f2bf(v.z); pk.w = f2bf(v.w);
                *(ushort4*)(&u.lw[r][j * 64 + inner * 4]) = pk;
            }
        }
        if (tid < 32) cs[tid] = comb[s0 + tid];
        __syncthreads();

        bf16x8 af[8];
        #pragma unroll
        for (int kk = 0; kk < 8; ++kk)
            af[kk] = *(const bf16x8*)(&u.lw[shalf + m][kk * 32 + quad * 8]);
        __syncthreads();   // lw reads done everywhere; lgt may now overwrite it

        #pragma unroll
        for (int t = 0; t < 8; ++t) {
            const int brow = bhalf + t * 16 + m;
            const unsigned short* bp = inbf + brow * DIM;
            bf16x8 bf[8];
            #pragma unroll
            for (int kk = 0; kk < 8; ++kk)
                bf[kk] = *(const bf16x8*)(bp + kk * 32 + quad * 8);
            f32x4 acc = {0, 0, 0, 0};
            #pragma unroll
            for (int kk = 0; kk < 8; ++kk)
                acc = __builtin_amdgcn_mfma_f32_16x16x32_bf16(af[kk], bf[kk], acc, 0, 0, 0);
            #pragma unroll
            for (int r = 0; r < 4; ++r)
                u.lgt[shalf + quad * 4 + r][brow] = acc[r] + cs[shalf + quad * 4 + r];
        }
        __syncthreads();

        // pair epilogue: ~84 pairs/bucket, logits already in LDS
        int n = cursor[tb];
        n = (n < CAP) ? n : CAP;
        const unsigned int* pb = pairs + (size_t)tb * CAP;
        for (int p = tid; p < n; p += 256) {
            const unsigned int pk = pb[p];
            const int b = pk >> 17;
            const int r = pk & 31;
            const float l = u.lgt[r][b];
            const float v = fmaxf(l, 0.0f) - l * (1.0f / (float)NUM_TRUE)
                          + __logf(1.0f + __expf(-fabsf(l)));
            atomicAdd(&bacc[b], v);
        }
        __syncthreads();
        ptrue[tid * NB2 + tb] = bacc[tid];   // [b][bucket], non-atomic
    }
}

// ---- final reduce: out[b] = 512 sampled partials + 3125 bucket partials ----
__global__ __launch_bounds__(256) void reduce_kernel(const float* __restrict__ partial,
                                                     const float* __restrict__ ptrue,
                                                     float* __restrict__ out) {
    __shared__ float wsum[4];
    const int b = blockIdx.x;
    const int tid = threadIdx.x;
    float v = partial[b * SBLOCKS + tid] + partial[b * SBLOCKS + 256 + tid];
    #pragma unroll
    for (int i = 0; i < 13; ++i) {
        const int k = i * 256 + tid;         // coalesced across threads
        if (k < NBUCKET) v += ptrue[b * NB2 + k];
    }
    v += __shfl_xor(v, 1);  v += __shfl_xor(v, 2);  v += __shfl_xor(v, 4);
    v += __shfl_xor(v, 8);  v += __shfl_xor(v, 16); v += __shfl_xor(v, 32);
    if ((tid & 63) == 0) wsum[tid >> 6] = v;
    __syncthreads();
    if (tid == 0) out[b] = wsum[0] + wsum[1] + wsum[2] + wsum[3];
}

extern "C" void kernel_launch(void* const* d_in, const int* in_sizes, int n_in,
                              void* d_out, int out_size, void* d_ws, size_t ws_size,
                              hipStream_t stream) {
    const float* inputs  = (const float*)d_in[0];   // [256,256]
    const float* w       = (const float*)d_in[1];   // [100000,256]
    const float* bias    = (const float*)d_in[2];   // [100000]
    const int*   labels  = (const int*)d_in[3];     // [256,1024]
    const int*   sampled = (const int*)d_in[4];     // [16384]
    float* out = (float*)d_out;                     // [256]

    float*          comb    = (float*)d_ws;                               // 400000 B
    unsigned short* inbf    = (unsigned short*)((char*)d_ws + 409600);    // 128 KB
    float*          partial = (float*)((char*)d_ws + 540672);             // 512 KB
    float*          ptrue   = (float*)((char*)d_ws + 1064960);            // 3.4 MB
    int*            cursor  = (int*)((char*)d_ws + 4472832);              // 12.5 KB
    unsigned int*   pairs   = (unsigned int*)((char*)d_ws + 4485632);     // 6.4 MB

    hipMemsetAsync(cursor, 0, NBUCKET * sizeof(int), stream);
    comb_kernel<<<(NUM_CLASSES + 255) / 256, 256, 0, stream>>>(bias, inputs, labels,
                                                               comb, inbf, cursor, pairs);
    fused_kernel<<<SBLOCKS + NBUCKET, 256, 0, stream>>>(inputs, w, comb, sampled,
                                                        inbf, cursor, pairs, ptrue, partial);
    reduce_kernel<<<BATCH, 256, 0, stream>>>(partial, ptrue, out);
}

// Round 8
// 239.042 us; speedup vs baseline: 1.1826x; 1.1826x over previous
//
#include <hip/hip_runtime.h>
#include <hip/hip_bf16.h>

#define NUM_CLASSES 100000
#define DIM 256
#define BATCH 256
#define NUM_TRUE 1024
#define NUM_SAMPLED 16384
// ln(NUM_CLASSES + 1)
#define LOG_RANGE 11.51293546492023f
#define INV_LOG_RANGE (1.0f / LOG_RANGE)

#define NBUCKET 3125     // class buckets of 32 sequential classes (100000 = 3125*32)
#define CAP     512      // pair slots per bucket (uniform labels: mean 84, max ~125)
#define COMB_THREADS 100096  // 391 blocks * 256

typedef __bf16 bf16x8 __attribute__((ext_vector_type(8)));
typedef float  f32x4  __attribute__((ext_vector_type(4)));

// RNE float -> bf16 bits
static __device__ __forceinline__ unsigned short f2bf(float f) {
    unsigned int u = __float_as_uint(f);
    unsigned int lsb = (u >> 16) & 1u;
    u += 0x7fffu + lsb;
    return (unsigned short)(u >> 16);
}

// -log(expected_count(id)), precise libm (once per class, comb_kernel only)
static __device__ __forceinline__ float neg_log_ec(int id) {
    float idf = (float)id;
    float p = logf((idf + 2.0f) / (idf + 1.0f)) * INV_LOG_RANGE;
    float ec = -expm1f((float)NUM_SAMPLED * log1pf(-p));
    return -logf(ec);
}

// ---- comb[c] = bias[c] - log(ec(c)); inputs fp32 -> bf16; sampled flag scatter;
//      bin all (b,label) pairs into class-range buckets (cursor+sam pre-zeroed) ----
__global__ __launch_bounds__(256) void comb_kernel(const float* __restrict__ bias,
                                                   const float* __restrict__ inputs,
                                                   const int* __restrict__ labels,
                                                   const int* __restrict__ sampled,
                                                   float* __restrict__ comb,
                                                   unsigned short* __restrict__ inbf,
                                                   unsigned char* __restrict__ sam,
                                                   int* __restrict__ cursor,
                                                   unsigned int* __restrict__ pairs) {
    int c = blockIdx.x * 256 + threadIdx.x;
    if (c < NUM_CLASSES) comb[c] = bias[c] + neg_log_ec(c);
    if (c < BATCH * DIM) inbf[c] = f2bf(inputs[c]);
    if (c < NUM_SAMPLED) sam[sampled[c]] = 1;   // sampled ids are unique
    for (int g = c; g < BATCH * NUM_TRUE; g += COMB_THREADS) {
        int lbl = labels[g];
        int bk = lbl >> 5;
        int pos = atomicAdd(&cursor[bk], 1);
        if (pos < CAP)
            pairs[(size_t)bk * CAP + pos] = ((unsigned int)(g >> 10) << 17) | (unsigned int)lbl;
    }
}

// ---------------- unified dense kernel: 3125 bucket blocks -----------------
// Each block: stream its 32 SEQUENTIAL w rows -> bf16 LDS (w read exactly once,
// coalesced, grid-wide = one 100 MB pass), dense MFMA vs all 256 batch cols
// (each wave owns 64 exclusive cols -> inbf read once per block, 128 KB),
// logits -> LDS; epilogue adds sampled-xent for flagged rows + true-pair xent.
__global__ __launch_bounds__(256) void fused_kernel(const float* __restrict__ w,
                                                    const float* __restrict__ comb,
                                                    const unsigned short* __restrict__ inbf,
                                                    const unsigned char* __restrict__ sam,
                                                    const int* __restrict__ cursor,
                                                    const unsigned int* __restrict__ pairs,
                                                    float* __restrict__ ptrue) {
    __shared__ unsigned short lw[32][264];   // staged w rows, bf16 (16.9 KB)
    __shared__ float lgt[BATCH][33];         // logits, stride 33 (33.8 KB, banks <=2-way)
    __shared__ float cs[32];
    __shared__ int   sf[32];
    __shared__ float bacc[BATCH];

    const int tid = threadIdx.x;
    const int tb  = blockIdx.x;
    const int s0  = tb * 32;

    int n = cursor[tb];                      // issue early, used in epilogue
    n = (n < CAP) ? n : CAP;

    bacc[tid] = 0.0f;

    // stage 32 sequential w rows -> bf16 LDS (fully coalesced 32 KB stream)
    const int inner = tid & 15;
    const int r16   = tid >> 4;
    const float* wb = w + (size_t)s0 * DIM;
    #pragma unroll
    for (int rb = 0; rb < 2; ++rb) {
        const int r = rb * 16 + r16;
        const float* src = wb + r * DIM;
        #pragma unroll
        for (int j = 0; j < 4; ++j) {
            float4 v = *(const float4*)(src + j * 64 + inner * 4);
            ushort4 pk;
            pk.x = f2bf(v.x); pk.y = f2bf(v.y); pk.z = f2bf(v.z); pk.w = f2bf(v.w);
            *(ushort4*)(&lw[r][j * 64 + inner * 4]) = pk;
        }
    }
    if (tid < 32) {
        cs[tid] = comb[s0 + tid];
        sf[tid] = (int)sam[s0 + tid];
    }
    __syncthreads();

    const int lane = tid & 63;
    const int wv   = tid >> 6;       // wave owns batch cols [wv*64, wv*64+64)
    const int m    = lane & 15;
    const int quad = lane >> 4;
    const int rb0  = quad * 4;

    // A-fragments for BOTH row-groups, held in registers (w rows via m)
    bf16x8 af0[8], af1[8];
    #pragma unroll
    for (int kk = 0; kk < 8; ++kk) {
        af0[kk] = *(const bf16x8*)(&lw[m][kk * 32 + quad * 8]);
        af1[kk] = *(const bf16x8*)(&lw[16 + m][kk * 32 + quad * 8]);
    }
    // comb values for this lane's output rows
    float cs0[4], cs1[4];
    #pragma unroll
    for (int r = 0; r < 4; ++r) { cs0[r] = cs[rb0 + r]; cs1[r] = cs[16 + rb0 + r]; }

    #pragma unroll
    for (int t = 0; t < 4; ++t) {
        const int brow = wv * 64 + t * 16 + m;
        const unsigned short* bp = inbf + brow * DIM;
        bf16x8 bf[8];
        #pragma unroll
        for (int kk = 0; kk < 8; ++kk)
            bf[kk] = *(const bf16x8*)(bp + kk * 32 + quad * 8);
        f32x4 a0 = {0, 0, 0, 0}, a1 = {0, 0, 0, 0};
        #pragma unroll
        for (int kk = 0; kk < 8; ++kk) {
            a0 = __builtin_amdgcn_mfma_f32_16x16x32_bf16(af0[kk], bf[kk], a0, 0, 0, 0);
            a1 = __builtin_amdgcn_mfma_f32_16x16x32_bf16(af1[kk], bf[kk], a1, 0, 0, 0);
        }
        // C/D: row(s) = quad*4 + r (+16 for group 1), col(b) = m -> brow
        #pragma unroll
        for (int r = 0; r < 4; ++r) {
            lgt[brow][rb0 + r]      = a0[r] + cs0[r];
            lgt[brow][16 + rb0 + r] = a1[r] + cs1[r];
        }
    }
    __syncthreads();

    // sampled epilogue: this thread owns batch col = tid; rows flagged sampled
    float ps = 0.0f;
    for (int r = 0; r < 32; ++r) {
        if (sf[r]) {
            const float l = lgt[tid][r];
            ps += fmaxf(l, 0.0f) + __logf(1.0f + __expf(-fabsf(l)));
        }
    }
    // true-pair epilogue: ~84 pairs, logits already in LDS
    const unsigned int* pb = pairs + (size_t)tb * CAP;
    for (int p = tid; p < n; p += 256) {
        const unsigned int pk = pb[p];
        const int b = pk >> 17;
        const int r = pk & 31;
        const float l = lgt[b][r];
        const float v = fmaxf(l, 0.0f) - l * (1.0f / (float)NUM_TRUE)
                      + __logf(1.0f + __expf(-fabsf(l)));
        atomicAdd(&bacc[b], v);
    }
    __syncthreads();
    ptrue[(size_t)tb * 256 + tid] = ps + bacc[tid];   // block-exclusive coalesced row
}

// ---- final reduce: out[b] = sum over 3125 buckets of ptrue[tb][b] ----
__global__ __launch_bounds__(256) void reduce_kernel(const float* __restrict__ ptrue,
                                                     float* __restrict__ out) {
    __shared__ float wsum[4];
    const int b = blockIdx.x;
    const int tid = threadIdx.x;
    float v = 0.0f;
    #pragma unroll
    for (int i = 0; i < 13; ++i) {
        const int k = tid + i * 256;
        if (k < NBUCKET) v += ptrue[(size_t)k * 256 + b];
    }
    v += __shfl_xor(v, 1);  v += __shfl_xor(v, 2);  v += __shfl_xor(v, 4);
    v += __shfl_xor(v, 8);  v += __shfl_xor(v, 16); v += __shfl_xor(v, 32);
    if ((tid & 63) == 0) wsum[tid >> 6] = v;
    __syncthreads();
    if (tid == 0) out[b] = wsum[0] + wsum[1] + wsum[2] + wsum[3];
}

extern "C" void kernel_launch(void* const* d_in, const int* in_sizes, int n_in,
                              void* d_out, int out_size, void* d_ws, size_t ws_size,
                              hipStream_t stream) {
    const float* inputs  = (const float*)d_in[0];   // [256,256]
    const float* w       = (const float*)d_in[1];   // [100000,256]
    const float* bias    = (const float*)d_in[2];   // [100000]
    const int*   labels  = (const int*)d_in[3];     // [256,1024]
    const int*   sampled = (const int*)d_in[4];     // [16384]
    float* out = (float*)d_out;                     // [256]

    float*          comb   = (float*)d_ws;                               // 400000 B
    unsigned short* inbf   = (unsigned short*)((char*)d_ws + 409600);    // 131072 B
    float*          ptrue  = (float*)((char*)d_ws + 540672);             // 3200000 B
    int*            cursor = (int*)((char*)d_ws + 3740672);              // 12544 B
    unsigned char*  sam    = (unsigned char*)((char*)d_ws + 3753216);    // 100000 B
    unsigned int*   pairs  = (unsigned int*)((char*)d_ws + 3853216);     // 6400000 B

    // zero cursor + sam in one contiguous memset
    hipMemsetAsync((char*)d_ws + 3740672, 0, 12544 + 100000, stream);
    comb_kernel<<<COMB_THREADS / 256, 256, 0, stream>>>(bias, inputs, labels, sampled,
                                                        comb, inbf, sam, cursor, pairs);
    fused_kernel<<<NBUCKET, 256, 0, stream>>>(w, comb, inbf, sam, cursor, pairs, ptrue);
    reduce_kernel<<<BATCH, 256, 0, stream>>>(ptrue, out);
}